// Round 1
// baseline (2793.657 us; speedup 1.0000x reference)
//
#include <hip/hip_runtime.h>
#include <math.h>

#define HH  64
#define GG  256          // 4*H gates
#define TT  2048
#define IND 7

__device__ __forceinline__ float fsigmoid(float x) {
    return 1.0f / (1.0f + __expf(-x));
}
__device__ __forceinline__ float ftanh_fast(float x) {
    float t = __expf(-2.0f * fabsf(x));
    float r = (1.0f - t) / (1.0f + t);
    return copysignf(r, x);
}

__global__ __launch_bounds__(256, 1) void lstm2_fused(
    const float* __restrict__ x,     // (B,7,2048)
    const float* __restrict__ Wih0,  // (256,7)
    const float* __restrict__ Whh0,  // (256,64)
    const float* __restrict__ bih0, const float* __restrict__ bhh0,
    const float* __restrict__ Wih1,  // (256,64)
    const float* __restrict__ Whh1,  // (256,64)
    const float* __restrict__ bih1, const float* __restrict__ bhh1,
    const float* __restrict__ W1,    // (10,64)
    const float* __restrict__ b1v,   // (10)
    const float* __restrict__ gmma, const float* __restrict__ beta,
    const float* __restrict__ rm,   const float* __restrict__ rv,
    const float* __restrict__ W2,   // (1,10)
    const float* __restrict__ b2,   // (1)
    float* __restrict__ out)         // (B,1)
{
    const int b = blockIdx.x;
    const int g = threadIdx.x;       // gate index 0..255
    const int j = g & (HH - 1);
    const int sector = g >> 6;       // 0:i 1:f 2:g 3:o  (wave-uniform)

    __shared__ float xbuf[IND * TT];   // 57344 B
    __shared__ float h0s[HH];
    __shared__ float h1s[HH];
    __shared__ float act0[GG];
    __shared__ float act1[GG];
    __shared__ float yv[16];

    // ---- stage x[b] (contiguous 7*2048 floats) into LDS, coalesced ----
    {
        const float4* src = (const float4*)(x + (size_t)b * (IND * TT));
        float4* dst = (float4*)xbuf;
        #pragma unroll
        for (int i = 0; i < (IND * TT / 4) / GG; ++i) {   // 14 iters
            dst[g + i * GG] = src[g + i * GG];
        }
    }

    // ---- per-thread weight rows into registers (~200 VGPRs) ----
    float w0[IND];
    #pragma unroll
    for (int d = 0; d < IND; ++d) w0[d] = Wih0[g * IND + d];

    float u0[HH], w1[HH], u1[HH];
    {
        const float4* p = (const float4*)(Whh0 + g * HH);
        #pragma unroll
        for (int k = 0; k < HH / 4; ++k) {
            float4 v = p[k];
            u0[4*k+0] = v.x; u0[4*k+1] = v.y; u0[4*k+2] = v.z; u0[4*k+3] = v.w;
        }
    }
    {
        const float4* p = (const float4*)(Wih1 + g * HH);
        #pragma unroll
        for (int k = 0; k < HH / 4; ++k) {
            float4 v = p[k];
            w1[4*k+0] = v.x; w1[4*k+1] = v.y; w1[4*k+2] = v.z; w1[4*k+3] = v.w;
        }
    }
    {
        const float4* p = (const float4*)(Whh1 + g * HH);
        #pragma unroll
        for (int k = 0; k < HH / 4; ++k) {
            float4 v = p[k];
            u1[4*k+0] = v.x; u1[4*k+1] = v.y; u1[4*k+2] = v.z; u1[4*k+3] = v.w;
        }
    }

    const float b0g = bih0[g] + bhh0[g];
    const float b1g = bih1[g] + bhh1[g];

    float c0 = 0.0f, c1 = 0.0f;   // cell state for lane j (replicated per wave)
    if (g < HH) { h0s[g] = 0.0f; h1s[g] = 0.0f; }
    __syncthreads();

    for (int t = 0; t < TT; ++t) {
        // ---- layer 0 gates: a = b + Wih0[g,:]@x_t + Whh0[g,:]@h0 ----
        float a = b0g;
        #pragma unroll
        for (int d = 0; d < IND; ++d) a += w0[d] * xbuf[d * TT + t];
        #pragma unroll
        for (int k = 0; k < HH; ++k) a += u0[k] * h0s[k];
        act0[g] = (sector == 2) ? ftanh_fast(a) : fsigmoid(a);
        __syncthreads();

        // ---- layer 0 cell/hidden update (redundant across all 4 waves) ----
        {
            float iv = act0[j], fv = act0[HH + j], gv = act0[2 * HH + j], ov = act0[3 * HH + j];
            c0 = fv * c0 + iv * gv;
            float h0v = ov * ftanh_fast(c0);
            if (g < HH) h0s[g] = h0v;   // wave 0 publishes
        }
        __syncthreads();

        // ---- layer 1 gates: a1 = b + Wih1[g,:]@h0 + Whh1[g,:]@h1 ----
        float a1 = b1g;
        #pragma unroll
        for (int k = 0; k < HH; ++k) a1 += w1[k] * h0s[k];
        #pragma unroll
        for (int k = 0; k < HH; ++k) a1 += u1[k] * h1s[k];
        act1[g] = (sector == 2) ? ftanh_fast(a1) : fsigmoid(a1);
        __syncthreads();

        // ---- layer 1 update ----
        {
            float iv = act1[j], fv = act1[HH + j], gv = act1[2 * HH + j], ov = act1[3 * HH + j];
            c1 = fv * c1 + iv * gv;
            float h1v = ov * ftanh_fast(c1);
            if (g < HH) h1s[g] = h1v;
        }
        __syncthreads();
    }

    // ---- head: y = relu(bn(h1_last @ W1^T + b1)) @ W2^T + b2 ----
    if (g < 10) {
        float y = b1v[g];
        #pragma unroll
        for (int k = 0; k < HH; ++k) y += W1[g * HH + k] * h1s[k];
        y = (y - rm[g]) * rsqrtf(rv[g] + 1e-5f) * gmma[g] + beta[g];
        y = fmaxf(y, 0.0f);
        yv[g] = y * W2[g];
    }
    __syncthreads();
    if (g == 0) {
        float s = b2[0];
        #pragma unroll
        for (int k = 0; k < 10; ++k) s += yv[k];
        out[b] = s;
    }
}

extern "C" void kernel_launch(void* const* d_in, const int* in_sizes, int n_in,
                              void* d_out, int out_size, void* d_ws, size_t ws_size,
                              hipStream_t stream) {
    const float* x    = (const float*)d_in[0];
    const float* Wih0 = (const float*)d_in[1];
    const float* Whh0 = (const float*)d_in[2];
    const float* bih0 = (const float*)d_in[3];
    const float* bhh0 = (const float*)d_in[4];
    const float* Wih1 = (const float*)d_in[5];
    const float* Whh1 = (const float*)d_in[6];
    const float* bih1 = (const float*)d_in[7];
    const float* bhh1 = (const float*)d_in[8];
    const float* W1   = (const float*)d_in[9];
    const float* b1   = (const float*)d_in[10];
    const float* gmma = (const float*)d_in[11];
    const float* beta = (const float*)d_in[12];
    const float* rm   = (const float*)d_in[13];
    const float* rv   = (const float*)d_in[14];
    const float* W2   = (const float*)d_in[15];
    const float* b2   = (const float*)d_in[16];

    const int B = in_sizes[0] / (IND * TT);   // 256

    lstm2_fused<<<dim3(B), dim3(256), 0, stream>>>(
        x, Wih0, Whh0, bih0, bhh0, Wih1, Whh1, bih1, bhh1,
        W1, b1, gmma, beta, rm, rv, W2, b2, (float*)d_out);
}

// Round 2
// 2028.600 us; speedup vs baseline: 1.3771x; 1.3771x over previous
//
#include <hip/hip_runtime.h>
#include <math.h>

#define HH  64
#define TT  2048
#define IND 7
#define NT  512

typedef float f4 __attribute__((ext_vector_type(4)));

__device__ __forceinline__ f4 fma4(f4 a, f4 b, f4 c) {
#if defined(__has_builtin)
#if __has_builtin(__builtin_elementwise_fma)
    return __builtin_elementwise_fma(a, b, c);
#else
    f4 r; r.x = fmaf(a.x,b.x,c.x); r.y = fmaf(a.y,b.y,c.y);
    r.z = fmaf(a.z,b.z,c.z); r.w = fmaf(a.w,b.w,c.w); return r;
#endif
#else
    f4 r; r.x = fmaf(a.x,b.x,c.x); r.y = fmaf(a.y,b.y,c.y);
    r.z = fmaf(a.z,b.z,c.z); r.w = fmaf(a.w,b.w,c.w); return r;
#endif
}

// sigmoid / tanh through a single exp: tanh(a) = 2*sigmoid(2a) - 1
__device__ __forceinline__ float gate_act(float a, bool is_tanh) {
    float z = is_tanh ? 2.0f * a : a;
    float e = __expf(-z);
    float sg = __fdividef(1.0f, 1.0f + e);
    return is_tanh ? fmaf(2.0f, sg, -1.0f) : sg;
}
__device__ __forceinline__ float tanh_s(float c) {
    float e = __expf(-2.0f * c);
    return fmaf(2.0f, __fdividef(1.0f, 1.0f + e), -1.0f);
}
// select the value whose xor-offset index is m (0:self,1:^16,2:^32,3:^48)
__device__ __forceinline__ float pick4(float a0, float a1, float a2, float a3, int m) {
    float lo = (m & 1) ? a1 : a0;
    float hi = (m & 1) ? a3 : a2;
    return (m & 2) ? hi : lo;
}

__global__ __launch_bounds__(NT, 2) void lstm2_fused(
    const float* __restrict__ x,     // (B,7,2048)
    const float* __restrict__ Wih0,  // (256,7)
    const float* __restrict__ Whh0,  // (256,64)
    const float* __restrict__ bih0, const float* __restrict__ bhh0,
    const float* __restrict__ Wih1,  // (256,64)
    const float* __restrict__ Whh1,  // (256,64)
    const float* __restrict__ bih1, const float* __restrict__ bhh1,
    const float* __restrict__ W1,    // (10,64)
    const float* __restrict__ b1v,   // (10)
    const float* __restrict__ gmma, const float* __restrict__ beta,
    const float* __restrict__ rm,   const float* __restrict__ rv,
    const float* __restrict__ W2,   // (1,10)
    const float* __restrict__ b2,   // (1)
    float* __restrict__ out)         // (B,1)
{
    const int b    = blockIdx.x;
    const int tid  = threadIdx.x;
    const int wave = tid >> 6;
    const int lane = tid & 63;
    const int s    = lane >> 4;        // sector: 0=i 1=f 2=g 3=o
    const int h    = lane & 1;         // k-half
    const int u    = (lane >> 1) & 7;  // unit within wave
    const int j    = (wave << 3) | u;  // hidden unit 0..63
    const int g    = (s << 6) | j;     // gate row 0..255

    __shared__ __align__(16) float xT[TT][8];     // 64 KB, xT[t][d], d=7 zero pad
    __shared__ __align__(16) float h0s[2][HH];
    __shared__ __align__(16) float h1s[2][HH];
    __shared__ float yv[10];

    // ---- stage x[b] transposed: global coalesced read, LDS [t][d] write ----
    {
        const float* xg = x + (size_t)b * (IND * TT);
        for (int i = tid; i < IND * TT; i += NT) {
            int d = i >> 11;          // /2048
            int t = i & (TT - 1);
            xT[t][d] = xg[i];
        }
        for (int t = tid; t < TT; t += NT) xT[t][7] = 0.0f;
        if (tid < HH) h1s[1][tid] = 0.0f;   // h1(-1) = 0
    }

    // ---- per-thread weight half-rows into registers (~100 floats) ----
    f4 u0r[8], w1r[8], u1r[8];
    {
        const f4* p0 = (const f4*)(Whh0 + g * HH + 32 * h);
        const f4* p1 = (const f4*)(Wih1 + g * HH + 32 * h);
        const f4* p2 = (const f4*)(Whh1 + g * HH + 32 * h);
        #pragma unroll
        for (int r = 0; r < 8; ++r) { u0r[r] = p0[r]; w1r[r] = p1[r]; u1r[r] = p2[r]; }
    }
    f4 xw;
    if (h == 0) { xw.x = Wih0[g*IND+0]; xw.y = Wih0[g*IND+1]; xw.z = Wih0[g*IND+2]; xw.w = Wih0[g*IND+3]; }
    else        { xw.x = Wih0[g*IND+4]; xw.y = Wih0[g*IND+5]; xw.z = Wih0[g*IND+6]; xw.w = 0.0f; }
    const float bg0 = (h == 0) ? (bih0[g] + bhh0[g]) : 0.0f;
    const float bg1 = (h == 0) ? (bih1[g] + bhh1[g]) : 0.0f;

    f4 h0q[8], h1q[8];
    #pragma unroll
    for (int r = 0; r < 8; ++r) {
        h0q[r].x = h0q[r].y = h0q[r].z = h0q[r].w = 0.0f;
        h1q[r].x = h1q[r].y = h1q[r].z = h1q[r].w = 0.0f;
    }
    float c0 = 0.0f, c1 = 0.0f;
    const bool is_t = (s == 2);
    const bool pub  = ((lane & 49) == 0);   // s==0 && h==0 lanes publish

    __syncthreads();

    for (int t = 0; t < TT; ++t) {
        const int p = t & 1;
        // ================= layer 0 (uses h0q = h0(t-1)) =================
        f4 a4; a4.x = bg0; a4.y = 0.f; a4.z = 0.f; a4.w = 0.f;
        f4 xq = *((const f4*)&xT[t][4 * h]);
        a4 = fma4(xw, xq, a4);
        #pragma unroll
        for (int r = 0; r < 8; ++r) a4 = fma4(u0r[r], h0q[r], a4);
        float ap = (a4.x + a4.y) + (a4.z + a4.w);
        float a  = ap + __shfl_xor(ap, 1);
        float act = gate_act(a, is_t);
        float v1 = __shfl_xor(act, 16);
        float v2 = __shfl_xor(act, 32);
        float v3 = __shfl_xor(act, 48);
        float iv = pick4(act, v1, v2, v3, s);
        float fv = pick4(act, v1, v2, v3, s ^ 1);
        float gv = pick4(act, v1, v2, v3, s ^ 2);
        float ov = pick4(act, v1, v2, v3, s ^ 3);
        c0 = fmaf(fv, c0, iv * gv);
        float h0new = ov * tanh_s(c0);
        if (pub) h0s[p][j] = h0new;
        __syncthreads();   // the only barrier per step
        // reload uniform chunks: h0(t) and h1(t-1)
        #pragma unroll
        for (int r = 0; r < 8; ++r) {
            h0q[r] = ((const f4*)&h0s[p][32 * h])[r];
            h1q[r] = ((const f4*)&h1s[p ^ 1][32 * h])[r];
        }
        // ================= layer 1 (uses h0(t), h1(t-1)) =================
        f4 b4; b4.x = bg1; b4.y = 0.f; b4.z = 0.f; b4.w = 0.f;
        #pragma unroll
        for (int r = 0; r < 8; ++r) b4 = fma4(w1r[r], h0q[r], b4);
        #pragma unroll
        for (int r = 0; r < 8; ++r) b4 = fma4(u1r[r], h1q[r], b4);
        float bp = (b4.x + b4.y) + (b4.z + b4.w);
        float ab = bp + __shfl_xor(bp, 1);
        float act1 = gate_act(ab, is_t);
        float q1 = __shfl_xor(act1, 16);
        float q2 = __shfl_xor(act1, 32);
        float q3 = __shfl_xor(act1, 48);
        float iv1 = pick4(act1, q1, q2, q3, s);
        float fv1 = pick4(act1, q1, q2, q3, s ^ 1);
        float gv1 = pick4(act1, q1, q2, q3, s ^ 2);
        float ov1 = pick4(act1, q1, q2, q3, s ^ 3);
        c1 = fmaf(fv1, c1, iv1 * gv1);
        float h1new = ov1 * tanh_s(c1);
        if (pub) h1s[p][j] = h1new;
        // no barrier here: h1s[p] is only read after the NEXT step's barrier
    }
    __syncthreads();

    // ---- head: y = relu(bn(h1_last @ W1^T + b1)) @ W2^T + b2 ----
    if (tid < 10) {
        float y = b1v[tid];
        #pragma unroll
        for (int k = 0; k < HH; ++k) y += W1[tid * HH + k] * h1s[1][k];  // (TT-1)&1 == 1
        y = (y - rm[tid]) * rsqrtf(rv[tid] + 1e-5f) * gmma[tid] + beta[tid];
        y = fmaxf(y, 0.0f);
        yv[tid] = y * W2[tid];
    }
    __syncthreads();
    if (tid == 0) {
        float sacc = b2[0];
        #pragma unroll
        for (int k = 0; k < 10; ++k) sacc += yv[k];
        out[b] = sacc;
    }
}

extern "C" void kernel_launch(void* const* d_in, const int* in_sizes, int n_in,
                              void* d_out, int out_size, void* d_ws, size_t ws_size,
                              hipStream_t stream) {
    const float* x    = (const float*)d_in[0];
    const float* Wih0 = (const float*)d_in[1];
    const float* Whh0 = (const float*)d_in[2];
    const float* bih0 = (const float*)d_in[3];
    const float* bhh0 = (const float*)d_in[4];
    const float* Wih1 = (const float*)d_in[5];
    const float* Whh1 = (const float*)d_in[6];
    const float* bih1 = (const float*)d_in[7];
    const float* bhh1 = (const float*)d_in[8];
    const float* W1   = (const float*)d_in[9];
    const float* b1   = (const float*)d_in[10];
    const float* gmma = (const float*)d_in[11];
    const float* beta = (const float*)d_in[12];
    const float* rm   = (const float*)d_in[13];
    const float* rv   = (const float*)d_in[14];
    const float* W2   = (const float*)d_in[15];
    const float* b2   = (const float*)d_in[16];

    const int B = in_sizes[0] / (IND * TT);   // 256

    lstm2_fused<<<dim3(B), dim3(NT), 0, stream>>>(
        x, Wih0, Whh0, bih0, bhh0, Wih1, Whh1, bih1, bhh1,
        W1, b1, gmma, beta, rm, rv, W2, b2, (float*)d_out);
}

// Round 3
// 1921.688 us; speedup vs baseline: 1.4538x; 1.0556x over previous
//
#include <hip/hip_runtime.h>
#include <math.h>

#define HH  64
#define TT  2048
#define IND 7
#define NT  512

typedef float f4 __attribute__((ext_vector_type(4)));

__device__ __forceinline__ f4 fma4(f4 a, f4 b, f4 c) {
    return __builtin_elementwise_fma(a, b, c);
}

// sigmoid / tanh through a single exp: tanh(a) = 2*sigmoid(2a) - 1
__device__ __forceinline__ float gate_act(float a, bool is_tanh) {
    float z = is_tanh ? 2.0f * a : a;
    float e = __expf(-z);
    float sg = __fdividef(1.0f, 1.0f + e);
    return is_tanh ? fmaf(2.0f, sg, -1.0f) : sg;
}
__device__ __forceinline__ float tanh_s(float c) {
    float e = __expf(-2.0f * c);
    return fmaf(2.0f, __fdividef(1.0f, 1.0f + e), -1.0f);
}
// select the value whose xor-offset index is m (0:self,1:^16,2:^32,3:^48)
__device__ __forceinline__ float pick4(float a0, float a1, float a2, float a3, int m) {
    float lo = (m & 1) ? a1 : a0;
    float hi = (m & 1) ? a3 : a2;
    return (m & 2) ? hi : lo;
}

__global__ __launch_bounds__(NT) __attribute__((amdgpu_waves_per_eu(2, 2)))
void lstm2_fused(
    const float* __restrict__ x,     // (B,7,2048)
    const float* __restrict__ Wih0,  // (256,7)
    const float* __restrict__ Whh0,  // (256,64)
    const float* __restrict__ bih0, const float* __restrict__ bhh0,
    const float* __restrict__ Wih1,  // (256,64)
    const float* __restrict__ Whh1,  // (256,64)
    const float* __restrict__ bih1, const float* __restrict__ bhh1,
    const float* __restrict__ W1,    // (10,64)
    const float* __restrict__ b1v,   // (10)
    const float* __restrict__ gmma, const float* __restrict__ beta,
    const float* __restrict__ rm,   const float* __restrict__ rv,
    const float* __restrict__ W2,   // (1,10)
    const float* __restrict__ b2,   // (1)
    float* __restrict__ out)         // (B,1)
{
    const int b    = blockIdx.x;
    const int tid  = threadIdx.x;
    const int wave = tid >> 6;
    const int lane = tid & 63;
    const int s    = lane >> 4;        // sector: 0=i 1=f 2=g 3=o
    const int h    = lane & 1;         // k-half
    const int u    = (lane >> 1) & 7;  // unit within wave
    const int j    = (wave << 3) | u;  // hidden unit 0..63
    const int g    = (s << 6) | j;     // gate row 0..255

    __shared__ __align__(16) float xT[TT][8];     // 64 KB, xT[t][d], d=7 zero pad
    __shared__ __align__(16) float h0s[2][HH];
    __shared__ __align__(16) float h1s[2][HH];
    __shared__ float yv[10];

    // ---- stage x[b] transposed: global coalesced read, LDS [t][d] write ----
    {
        const float* xg = x + (size_t)b * (IND * TT);
        for (int i = tid; i < IND * TT; i += NT) {
            int d = i >> 11;          // /2048
            int t = i & (TT - 1);
            xT[t][d] = xg[i];
        }
        for (int t = tid; t < TT; t += NT) xT[t][7] = 0.0f;
        if (tid < HH) { h0s[1][tid] = 0.0f; h1s[1][tid] = 0.0f; }
    }

    // ---- per-thread weight half-rows into registers (~100 floats) ----
    f4 u0r[8], w1r[8], u1r[8];
    {
        const f4* p0 = (const f4*)(Whh0 + g * HH + 32 * h);
        const f4* p1 = (const f4*)(Wih1 + g * HH + 32 * h);
        const f4* p2 = (const f4*)(Whh1 + g * HH + 32 * h);
        #pragma unroll
        for (int r = 0; r < 8; ++r) { u0r[r] = p0[r]; w1r[r] = p1[r]; u1r[r] = p2[r]; }
    }
    f4 xw;
    if (h == 0) { xw.x = Wih0[g*IND+0]; xw.y = Wih0[g*IND+1]; xw.z = Wih0[g*IND+2]; xw.w = Wih0[g*IND+3]; }
    else        { xw.x = Wih0[g*IND+4]; xw.y = Wih0[g*IND+5]; xw.z = Wih0[g*IND+6]; xw.w = 0.0f; }
    const float bg0 = (h == 0) ? (bih0[g] + bhh0[g]) : 0.0f;
    const float bg1 = (h == 0) ? (bih1[g] + bhh1[g]) : 0.0f;

    // h0q caches h0(t-1) chunk [32h .. 32h+31] across iterations
    f4 h0q[8];
    #pragma unroll
    for (int r = 0; r < 8; ++r) h0q[r] = (f4)(0.0f);

    float c0 = 0.0f, c1 = 0.0f;
    const bool is_t = (s == 2);
    const bool pub  = ((lane & 49) == 0);   // s==0 && h==0 lanes publish

    __syncthreads();

    for (int t = 0; t < TT; ++t) {
        const int p = t & 1;
        // ================= layer 0 (uses h0q = h0(t-1), registers) ==========
        f4 xq = *((const f4*)&xT[t][4 * h]);
        f4 a0; a0.x = bg0; a0.y = 0.f; a0.z = 0.f; a0.w = 0.f;
        a0 = fma4(xw, xq, a0);
        f4 a1 = (f4)(0.0f);
        #pragma unroll
        for (int r = 0; r < 8; r += 2) {
            a0 = fma4(u0r[r],     h0q[r],     a0);
            a1 = fma4(u0r[r + 1], h0q[r + 1], a1);
        }
        f4 am = a0 + a1;
        float ap = (am.x + am.y) + (am.z + am.w);
        float a  = ap + __shfl_xor(ap, 1);
        float act = gate_act(a, is_t);
        float v1 = __shfl_xor(act, 16);
        float v2 = __shfl_xor(act, 32);
        float v3 = __shfl_xor(act, 48);
        float iv = pick4(act, v1, v2, v3, s);
        float fv = pick4(act, v1, v2, v3, s ^ 1);
        float gv = pick4(act, v1, v2, v3, s ^ 2);
        float ov = pick4(act, v1, v2, v3, s ^ 3);
        c0 = fmaf(fv, c0, iv * gv);
        float h0new = ov * tanh_s(c0);
        if (pub) h0s[p][j] = h0new;
        __syncthreads();   // the only barrier per step

        // ===== layer 1: read h0(t) into h0q (reused next step) + h1(t-1) ====
        const f4* hp0 = (const f4*)&h0s[p][32 * h];
        const f4* hp1 = (const f4*)&h1s[p ^ 1][32 * h];
        f4 b0; b0.x = bg1; b0.y = 0.f; b0.z = 0.f; b0.w = 0.f;
        f4 b1 = (f4)(0.0f);
        #pragma unroll
        for (int r = 0; r < 8; ++r) {
            h0q[r] = hp0[r];
            b0 = fma4(w1r[r], h0q[r], b0);
            b1 = fma4(u1r[r], hp1[r], b1);
        }
        f4 bm = b0 + b1;
        float bp = (bm.x + bm.y) + (bm.z + bm.w);
        float ab = bp + __shfl_xor(bp, 1);
        float act1 = gate_act(ab, is_t);
        float q1 = __shfl_xor(act1, 16);
        float q2 = __shfl_xor(act1, 32);
        float q3 = __shfl_xor(act1, 48);
        float iv1 = pick4(act1, q1, q2, q3, s);
        float fv1 = pick4(act1, q1, q2, q3, s ^ 1);
        float gv1 = pick4(act1, q1, q2, q3, s ^ 2);
        float ov1 = pick4(act1, q1, q2, q3, s ^ 3);
        c1 = fmaf(fv1, c1, iv1 * gv1);
        float h1new = ov1 * tanh_s(c1);
        if (pub) h1s[p][j] = h1new;
        // no barrier here: h1s[p] / h0s[p^1] are only touched again after the
        // NEXT step's barrier (double-buffered), so one barrier/step suffices
    }
    __syncthreads();

    // ---- head: y = relu(bn(h1_last @ W1^T + b1)) @ W2^T + b2 ----
    if (tid < 10) {
        float y = b1v[tid];
        #pragma unroll
        for (int k = 0; k < HH; ++k) y += W1[tid * HH + k] * h1s[1][k];  // (TT-1)&1 == 1
        y = (y - rm[tid]) * rsqrtf(rv[tid] + 1e-5f) * gmma[tid] + beta[tid];
        y = fmaxf(y, 0.0f);
        yv[tid] = y * W2[tid];
    }
    __syncthreads();
    if (tid == 0) {
        float sacc = b2[0];
        #pragma unroll
        for (int k = 0; k < 10; ++k) sacc += yv[k];
        out[b] = sacc;
    }
}

extern "C" void kernel_launch(void* const* d_in, const int* in_sizes, int n_in,
                              void* d_out, int out_size, void* d_ws, size_t ws_size,
                              hipStream_t stream) {
    const float* x    = (const float*)d_in[0];
    const float* Wih0 = (const float*)d_in[1];
    const float* Whh0 = (const float*)d_in[2];
    const float* bih0 = (const float*)d_in[3];
    const float* bhh0 = (const float*)d_in[4];
    const float* Wih1 = (const float*)d_in[5];
    const float* Whh1 = (const float*)d_in[6];
    const float* bih1 = (const float*)d_in[7];
    const float* bhh1 = (const float*)d_in[8];
    const float* W1   = (const float*)d_in[9];
    const float* b1   = (const float*)d_in[10];
    const float* gmma = (const float*)d_in[11];
    const float* beta = (const float*)d_in[12];
    const float* rm   = (const float*)d_in[13];
    const float* rv   = (const float*)d_in[14];
    const float* W2   = (const float*)d_in[15];
    const float* b2   = (const float*)d_in[16];

    const int B = in_sizes[0] / (IND * TT);   // 256

    lstm2_fused<<<dim3(B), dim3(NT), 0, stream>>>(
        x, Wih0, Whh0, bih0, bhh0, Wih1, Whh1, bih1, bhh1,
        W1, b1, gmma, beta, rm, rv, W2, b2, (float*)d_out);
}